// Round 3
// baseline (42092.142 us; speedup 1.0000x reference)
//
#include <hip/hip_runtime.h>

using half8 = __attribute__((ext_vector_type(8))) _Float16;
using f32x4 = __attribute__((ext_vector_type(4))) float;
typedef unsigned long long u64;

static constexpr int TT  = 2048;   // time steps
static constexpr int NB  = 16;     // batch
static constexpr int SS  = 512;    // state dim
static constexpr int NWG = 8;      // cooperative scan workgroups (64 cols each)

// -------------------- transpose + fp32->f16 (512x512): out[c][r] = in[r][c] --------------------
__global__ __launch_bounds__(256) void tcvt_kernel(const float* __restrict__ in,
                                                   _Float16* __restrict__ out) {
    __shared__ float tile[32][33];
    int bid = blockIdx.x;
    int rb = (bid >> 4) * 32, cb = (bid & 15) * 32;
    int tx = threadIdx.x & 31, ty = threadIdx.x >> 5;
    for (int rr = ty; rr < 32; rr += 8)
        tile[rr][tx] = in[(size_t)(rb + rr) * SS + cb + tx];
    __syncthreads();
    for (int rr = ty; rr < 32; rr += 8)
        out[(size_t)(cb + rr) * SS + rb + tx] = (_Float16)tile[tx][rr];
}

// -------------------- W = C0 @ B1 (512x512x512 fp32) --------------------
__global__ __launch_bounds__(256) void wmm_kernel(const float* __restrict__ C0,
                                                  const float* __restrict__ B1,
                                                  float* __restrict__ W) {
    int k = blockIdx.x;
    int tid = threadIdx.x;
    const float* crow = C0 + (size_t)k * SS;
    float s0 = 0.f, s1 = 0.f;
    for (int m = 0; m < SS; ++m) {
        float cv = crow[m];
        s0 += cv * B1[(size_t)m * SS + tid];
        s1 += cv * B1[(size_t)m * SS + tid + 256];
    }
    W[(size_t)k * SS + tid] = s0;
    W[(size_t)k * SS + tid + 256] = s1;
}

// -------------------- zero flags (must precede scans every launch: graph replay) ----------------
__global__ __launch_bounds__(512) void zinit_kernel(unsigned* __restrict__ p, int n) {
    int i = blockIdx.x * blockDim.x + threadIdx.x;
    if (i < n) p[i] = 0u;
}

// -------------------- big GEMM: M=32768(b*2048+t), N=512, K=512 --------------------
// BT: f16 [n][k]. ALAY 0: A fp32 [m][k]; ALAY 1: A f16 [m][k].
// MODE 0: f16 out[m][n]; MODE 1: fp32 out[m][n]; MODE 2: f16 out in scan layout [t][b][n].
template <int ALAY, int MODE>
__global__ __launch_bounds__(256) void gemm_kernel(const void* __restrict__ Aptr,
                                                   const _Float16* __restrict__ BT,
                                                   void* __restrict__ Outp) {
    int lane = threadIdx.x & 63;
    int wv   = threadIdx.x >> 6;
    int wid  = blockIdx.x * 4 + wv;
    int mt   = wid >> 3;
    int nb   = (wid & 7) * 64;
    int mbase = mt * 16;
    int lo = lane & 15, q = lane >> 4;

    f32x4 acc[4] = {{0,0,0,0},{0,0,0,0},{0,0,0,0},{0,0,0,0}};

    const float*    Af = (const float*)Aptr;
    const _Float16* Ah = (const _Float16*)Aptr;
    size_t arow = (size_t)(mbase + lo) * SS;

    #pragma unroll 2
    for (int kk = 0; kk < 16; ++kk) {
        int koff = kk * 32 + q * 8;
        half8 af;
        if (ALAY == 0) {
            const float* ar = Af + arow + koff;
            f32x4 a0 = *(const f32x4*)ar;
            f32x4 a1 = *(const f32x4*)(ar + 4);
            #pragma unroll
            for (int j = 0; j < 4; ++j) { af[j] = (_Float16)a0[j]; af[4 + j] = (_Float16)a1[j]; }
        } else {
            af = *(const half8*)(Ah + arow + koff);
        }
        #pragma unroll
        for (int j = 0; j < 4; ++j) {
            int n = nb + j * 16 + lo;
            half8 bf = *(const half8*)(BT + (size_t)n * SS + koff);
            acc[j] = __builtin_amdgcn_mfma_f32_16x16x32_f16(af, bf, acc[j], 0, 0, 0);
        }
    }

    #pragma unroll
    for (int j = 0; j < 4; ++j) {
        #pragma unroll
        for (int i = 0; i < 4; ++i) {
            int m = mbase + q * 4 + i;
            int n = nb + j * 16 + lo;
            if (MODE == 0) {
                ((_Float16*)Outp)[(size_t)m * SS + n] = (_Float16)acc[j][i];
            } else if (MODE == 1) {
                ((float*)Outp)[(size_t)m * SS + n] = acc[j][i];
            } else {
                int t2 = m & (TT - 1);
                int b2 = m >> 11;                 // T = 2048 = 2^11
                ((_Float16*)Outp)[((size_t)t2 * NB + b2) * SS + n] = (_Float16)acc[j][i];
            }
        }
    }
}

// -------------------- cooperative liquid scan: 8 WGs, weights in registers --------------------
// z is transported in FP32 (layer-1 z reaches ~1e6 — f16 overflows to Inf -> NaN; that was the
// round-1/2 failure). All cross-WG data moves via agent-scope atomics (coherence point).
// WG w owns state cols [64w, 64w+64). Waves 0-3 hold A/K slices in registers; per step:
// 32 MFMA -> z (fp32) -> LDS transpose -> atomic publish -> flag sync -> atomic gather ->
// replicated LN + exact GELU + h update (identical in all WGs) -> next step.
__global__ __launch_bounds__(512) void scan4_kernel(
        const _Float16* __restrict__ U,     // [T][NB][SS]
        const float* __restrict__ Amat,     // [SS][SS] fp32 (k-major rows)
        const float* __restrict__ Kmat,     // [SS][SS]
        const float* __restrict__ ab,
        const float* __restrict__ gn,
        const float* __restrict__ bt,
        _Float16* __restrict__ hs,          // [NB][T][SS] history out
        u64*      __restrict__ zmail,       // [2][NWG][512] u64  == [2][NWG][16][64] f32
        u64*      __restrict__ smail,       // [2][NWG][16] u64   == packed (S1,S2) f32 pairs
        unsigned* __restrict__ flags)       // [NWG][32] monotone step counters (128B stride)
{
    const int wg   = blockIdx.x;
    const int tid  = threadIdx.x;
    const int wv   = tid >> 6;
    const int lane = tid & 63;
    const int q    = lane >> 4;
    const int r    = lane & 15;

    __shared__ _Float16 H16[16][520];           // f16 H for MFMA A-frags
    __shared__ float    HF[16][516];            // fp32 master accumulator of H
    alignas(16) __shared__ float ZW32[16][64];  // own z slice staging (FP32)
    __shared__ float    STAT[4][16][2];         // per-MFMA-wave partial (S1,S2) per batch
    __shared__ float    MURS[16][2];            // mu, rsqrt(var+eps) per batch
    __shared__ float    GG[512];
    __shared__ float    BB[512];

    const int ub = tid & 15;            // h-update batch
    const int ug = tid >> 4;            // 0..31
    const int uc = ug * 16;             // h-update col start (slice index uc>>6 == wv)

    for (int e = tid; e < 16 * 520; e += 512) (&H16[0][0])[e] = (_Float16)0.f;
    for (int e = tid; e < 16 * 516; e += 512) (&HF[0][0])[e] = 0.f;
    GG[tid] = gn[tid];
    BB[tid] = bt[tid];

    const bool mf = (wv < 4);
    const int ccol = wg * 64 + (wv & 3) * 16 + r;

    // one-time weight preload into registers (f16)
    half8 wA[16], wK[16];
    if (mf) {
        for (int ks = 0; ks < 16; ++ks) {
            half8 a, k;
            #pragma unroll
            for (int jj = 0; jj < 8; ++jj) {
                int kk = ks * 32 + q * 8 + jj;
                a[jj] = (_Float16)Amat[(size_t)kk * SS + ccol];
                k[jj] = (_Float16)Kmat[(size_t)kk * SS + ccol];
            }
            wA[ks] = a; wK[ks] = k;
        }
    }
    const float abreg = ab[ccol];
    float uprev[4] = {0.f, 0.f, 0.f, 0.f};
    __syncthreads();

    for (int t = 0; t < TT; ++t) {
        const int par = t & 1;

        if (mf) {
            float ucur[4];
            #pragma unroll
            for (int i = 0; i < 4; ++i)
                ucur[i] = (float)U[((size_t)t * NB + (q * 4 + i)) * SS + ccol];

            f32x4 zA = {0.f, 0.f, 0.f, 0.f}, zK = {0.f, 0.f, 0.f, 0.f};
            #pragma unroll
            for (int ks = 0; ks < 16; ++ks) {
                half8 hf = *(const half8*)(&H16[r][ks * 32 + q * 8]);
                zA = __builtin_amdgcn_mfma_f32_16x16x32_f16(hf, wA[ks], zA, 0, 0, 0);
                zK = __builtin_amdgcn_mfma_f32_16x16x32_f16(hf, wK[ks], zK, 0, 0, 0);
            }

            float z[4];
            #pragma unroll
            for (int i = 0; i < 4; ++i) {
                z[i] = zA[i] + ucur[i] + abreg + zK[i] * uprev[i];
                uprev[i] = ucur[i];
                ZW32[q * 4 + i][(wv & 3) * 16 + r] = z[i];   // fp32 LDS transpose stage
            }

            // per-tile LN moments (fp32): reduce over 16 cols (r bits)
            float s1[4], s2[4];
            #pragma unroll
            for (int i = 0; i < 4; ++i) { s1[i] = z[i]; s2[i] = z[i] * z[i]; }
            #pragma unroll
            for (int off = 1; off < 16; off <<= 1) {
                #pragma unroll
                for (int i = 0; i < 4; ++i) {
                    s1[i] += __shfl_xor(s1[i], off, 64);
                    s2[i] += __shfl_xor(s2[i], off, 64);
                }
            }
            if (r == 0) {
                #pragma unroll
                for (int i = 0; i < 4; ++i) {
                    STAT[wv][q * 4 + i][0] = s1[i];
                    STAT[wv][q * 4 + i][1] = s2[i];
                }
            }
        }
        __builtin_amdgcn_s_waitcnt(0);
        __syncthreads();                                   // B1: ZW32/STAT ready

        // publish z slice: 512 threads x one contiguous 8B agent-scope atomic store (fp32 pairs)
        {
            u64 v = ((const u64*)ZW32)[tid];
            __hip_atomic_store(&zmail[((size_t)par * NWG + wg) * 512 + tid], v,
                               __ATOMIC_RELAXED, __HIP_MEMORY_SCOPE_AGENT);
        }
        // publish WG-partial LN moments: packed (S1,S2) u64 per batch
        if (wv == 0 && lane < 16) {
            float S1 = STAT[0][lane][0] + STAT[1][lane][0] + STAT[2][lane][0] + STAT[3][lane][0];
            float S2 = STAT[0][lane][1] + STAT[1][lane][1] + STAT[2][lane][1] + STAT[3][lane][1];
            union { float f[2]; u64 u; } pk;
            pk.f[0] = S1; pk.f[1] = S2;
            __hip_atomic_store(&smail[((size_t)par * NWG + wg) * 16 + lane], pk.u,
                               __ATOMIC_RELAXED, __HIP_MEMORY_SCOPE_AGENT);
        }
        __builtin_amdgcn_s_waitcnt(0);
        __syncthreads();                                   // B2: all publishes at coherence point

        if (tid == 0) {
            __builtin_amdgcn_fence(__ATOMIC_RELEASE, "agent");
            __hip_atomic_store(&flags[wg * 32], (unsigned)(t + 1),
                               __ATOMIC_RELAXED, __HIP_MEMORY_SCOPE_AGENT);
            #pragma unroll 1
            for (int i = 1; i < NWG; ++i) {
                unsigned* fp = &flags[((wg + i) & (NWG - 1)) * 32];
                while (__hip_atomic_load(fp, __ATOMIC_RELAXED, __HIP_MEMORY_SCOPE_AGENT)
                       < (unsigned)(t + 1)) {}
            }
            __builtin_amdgcn_fence(__ATOMIC_ACQUIRE, "agent");
        }
        __syncthreads();                                   // B3: all WGs published step t

        // gather this thread's 16 z values (batch ub, cols uc..uc+15), fp32
        float zz[16];
        if (wv == wg) {                                    // own slice: read LDS copy
            #pragma unroll
            for (int i = 0; i < 16; ++i) zz[i] = ZW32[ub][(uc & 63) + i];
        } else {
            union { u64 u[8]; float f[16]; } zu;
            const u64* src = &zmail[(((size_t)par * NWG + wv) * 16 + ub) * 32 + ((uc & 63) >> 1)];
            #pragma unroll
            for (int i = 0; i < 8; ++i)
                zu.u[i] = __hip_atomic_load(src + i, __ATOMIC_RELAXED, __HIP_MEMORY_SCOPE_AGENT);
            #pragma unroll
            for (int i = 0; i < 16; ++i) zz[i] = zu.f[i];
        }

        // global LN stats (identical summation order in every WG)
        if (wv == 0 && lane < 16) {
            float S1 = 0.f, S2 = 0.f;
            #pragma unroll 1
            for (int i = 0; i < NWG; ++i) {
                union { u64 u; float f[2]; } pk;
                pk.u = __hip_atomic_load(&smail[((size_t)par * NWG + i) * 16 + lane],
                                         __ATOMIC_RELAXED, __HIP_MEMORY_SCOPE_AGENT);
                S1 += pk.f[0]; S2 += pk.f[1];
            }
            float mu  = S1 * (1.0f / SS);
            float var = S2 * (1.0f / SS) - mu * mu;
            MURS[lane][0] = mu;
            MURS[lane][1] = rsqrtf(var + 1e-5f);
        }
        __syncthreads();                                   // B4: MURS ready

        // replicated LN + exact GELU + h update (16 elems/thread), identical in all WGs
        const float mu = MURS[ub][0], rs = MURS[ub][1];
        half8 hh0, hh1;
        #pragma unroll
        for (int i4 = 0; i4 < 4; ++i4) {
            f32x4 gq = *(const f32x4*)&GG[uc + i4 * 4];
            f32x4 bq = *(const f32x4*)&BB[uc + i4 * 4];
            f32x4 hq = *(const f32x4*)&HF[ub][uc + i4 * 4];
            #pragma unroll
            for (int jj = 0; jj < 4; ++jj) {
                const int e = i4 * 4 + jj;
                float zn = (zz[e] - mu) * rs * gq[jj] + bq[jj];
                float ge = 0.5f * zn * (1.0f + erff(zn * 0.70710678118654752f));
                float hv = hq[jj] + ge;
                hq[jj] = hv;
                if (e < 8) hh0[e] = (_Float16)hv; else hh1[e - 8] = (_Float16)hv;
            }
            *(f32x4*)&HF[ub][uc + i4 * 4] = hq;
        }
        *(half8*)(&H16[ub][uc])     = hh0;
        *(half8*)(&H16[ub][uc + 8]) = hh1;
        if (wv == wg) {   // slice owner writes history
            _Float16* hd = hs + ((size_t)ub * TT + t) * SS + uc;
            *(half8*)(hd)     = hh0;
            *(half8*)(hd + 8) = hh1;
        }
        __syncthreads();                                   // B5: H16/ZW32/STAT free for next step
    }
}

// -------------------- host launch --------------------
extern "C" void kernel_launch(void* const* d_in, const int* in_sizes, int n_in,
                              void* d_out, int out_size, void* d_ws, size_t ws_size,
                              hipStream_t stream) {
    const float* x   = (const float*)d_in[0];
    const float* A0  = (const float*)d_in[1];
    const float* B0  = (const float*)d_in[2];
    const float* C0  = (const float*)d_in[3];
    const float* K0  = (const float*)d_in[4];
    const float* ab0 = (const float*)d_in[5];
    const float* g0  = (const float*)d_in[6];
    const float* bt0 = (const float*)d_in[7];
    const float* A1  = (const float*)d_in[8];
    const float* B1  = (const float*)d_in[9];
    const float* C1  = (const float*)d_in[10];
    const float* K1  = (const float*)d_in[11];
    const float* ab1 = (const float*)d_in[12];
    const float* g1  = (const float*)d_in[13];
    const float* bt1 = (const float*)d_in[14];

    char* ws = (char*)d_ws;
    size_t off = 0;
    auto alloc = [&](size_t bytes) { size_t o = off; off = (off + bytes + 255) & ~(size_t)255; return o; };

    const size_t BUF_BYTES = (size_t)NB * TT * SS * 2;   // 33.5 MB f16
    const size_t WP_BYTES  = (size_t)SS * SS * 2;        // 512 KB f16

    _Float16* U0  = (_Float16*)(ws + alloc(BUF_BYTES));  // [t][b][c]
    _Float16* U1  = (_Float16*)(ws + alloc(BUF_BYTES));  // [t][b][c]
    _Float16* hs0 = (_Float16*)(ws + alloc(BUF_BYTES));  // [b][t][c]
    _Float16* hs1 = (_Float16*)(ws + alloc(BUF_BYTES));  // [b][t][c]
    _Float16* B0T = (_Float16*)(ws + alloc(WP_BYTES));
    _Float16* WT  = (_Float16*)(ws + alloc(WP_BYTES));
    _Float16* C1T = (_Float16*)(ws + alloc(WP_BYTES));
    float*    Wf  = (float*)(ws + alloc((size_t)SS * SS * 4));
    u64*      zmail  = (u64*)(ws + alloc((size_t)2 * NWG * 512 * 8));   // 64 KB
    u64*      smail  = (u64*)(ws + alloc((size_t)2 * NWG * 16 * 8));
    unsigned* flags0 = (unsigned*)(ws + alloc((size_t)NWG * 32 * 4));   // contiguous with flags1
    unsigned* flags1 = (unsigned*)(ws + alloc((size_t)NWG * 32 * 4));

    // zero both scans' flags first (stream-ordered; safe under graph replay)
    zinit_kernel<<<1, 512, 0, stream>>>(flags0, 2 * NWG * 32);
    (void)flags1;

    // weight preps
    tcvt_kernel<<<256, 256, 0, stream>>>(B0, B0T);
    tcvt_kernel<<<256, 256, 0, stream>>>(C1, C1T);
    wmm_kernel<<<512, 256, 0, stream>>>(C0, B1, Wf);     // W = C0 @ B1 (layer-fold)
    tcvt_kernel<<<256, 256, 0, stream>>>(Wf, WT);

    // U0 = x @ B0, scan layout [t][b][c]
    gemm_kernel<0, 2><<<4096, 256, 0, stream>>>((const void*)x, B0T, (void*)U0);

    // layer-0 cooperative scan
    scan4_kernel<<<NWG, 512, 0, stream>>>(U0, A0, K0, ab0, g0, bt0, hs0, zmail, smail, flags0);

    // U1 = hs0 @ (C0@B1), scan layout
    gemm_kernel<1, 2><<<4096, 256, 0, stream>>>((const void*)hs0, WT, (void*)U1);

    // layer-1 cooperative scan
    scan4_kernel<<<NWG, 512, 0, stream>>>(U1, A1, K1, ab1, g1, bt1, hs1, zmail, smail, flags1);

    // out = hs1 @ C1 (fp32 [b][t][c])
    gemm_kernel<1, 1><<<4096, 256, 0, stream>>>((const void*)hs1, C1T, d_out);
}

// Round 4
// 27017.526 us; speedup vs baseline: 1.5580x; 1.5580x over previous
//
#include <hip/hip_runtime.h>

using half8 = __attribute__((ext_vector_type(8))) _Float16;
using f32x4 = __attribute__((ext_vector_type(4))) float;
typedef unsigned long long u64;

static constexpr int TT  = 2048;   // time steps
static constexpr int NB  = 16;     // batch
static constexpr int SS  = 512;    // state dim
static constexpr int NWG = 8;      // cooperative scan workgroups (64 cols each)

// -------------------- transpose + fp32->f16 (512x512): out[c][r] = in[r][c] --------------------
__global__ __launch_bounds__(256) void tcvt_kernel(const float* __restrict__ in,
                                                   _Float16* __restrict__ out) {
    __shared__ float tile[32][33];
    int bid = blockIdx.x;
    int rb = (bid >> 4) * 32, cb = (bid & 15) * 32;
    int tx = threadIdx.x & 31, ty = threadIdx.x >> 5;
    for (int rr = ty; rr < 32; rr += 8)
        tile[rr][tx] = in[(size_t)(rb + rr) * SS + cb + tx];
    __syncthreads();
    for (int rr = ty; rr < 32; rr += 8)
        out[(size_t)(cb + rr) * SS + rb + tx] = (_Float16)tile[tx][rr];
}

// -------------------- W = C0 @ B1 (512x512x512 fp32) --------------------
__global__ __launch_bounds__(256) void wmm_kernel(const float* __restrict__ C0,
                                                  const float* __restrict__ B1,
                                                  float* __restrict__ W) {
    int k = blockIdx.x;
    int tid = threadIdx.x;
    const float* crow = C0 + (size_t)k * SS;
    float s0 = 0.f, s1 = 0.f;
    for (int m = 0; m < SS; ++m) {
        float cv = crow[m];
        s0 += cv * B1[(size_t)m * SS + tid];
        s1 += cv * B1[(size_t)m * SS + tid + 256];
    }
    W[(size_t)k * SS + tid] = s0;
    W[(size_t)k * SS + tid + 256] = s1;
}

// -------------------- zero flags (must precede scans every launch: graph replay) ----------------
__global__ __launch_bounds__(512) void zinit_kernel(unsigned* __restrict__ p, int n) {
    int i = blockIdx.x * blockDim.x + threadIdx.x;
    if (i < n) p[i] = 0u;
}

// -------------------- big GEMM: M=32768(b*2048+t), N=512, K=512 --------------------
// BT: f16 [n][k]. ALAY 0: A fp32 [m][k]; ALAY 1: A f16 [m][k].
// MODE 0: f16 out[m][n]; MODE 1: fp32 out[m][n]; MODE 2: f16 out in scan layout [t][b][n].
template <int ALAY, int MODE>
__global__ __launch_bounds__(256) void gemm_kernel(const void* __restrict__ Aptr,
                                                   const _Float16* __restrict__ BT,
                                                   void* __restrict__ Outp) {
    int lane = threadIdx.x & 63;
    int wv   = threadIdx.x >> 6;
    int wid  = blockIdx.x * 4 + wv;
    int mt   = wid >> 3;
    int nb   = (wid & 7) * 64;
    int mbase = mt * 16;
    int lo = lane & 15, q = lane >> 4;

    f32x4 acc[4] = {{0,0,0,0},{0,0,0,0},{0,0,0,0},{0,0,0,0}};

    const float*    Af = (const float*)Aptr;
    const _Float16* Ah = (const _Float16*)Aptr;
    size_t arow = (size_t)(mbase + lo) * SS;

    #pragma unroll 2
    for (int kk = 0; kk < 16; ++kk) {
        int koff = kk * 32 + q * 8;
        half8 af;
        if (ALAY == 0) {
            const float* ar = Af + arow + koff;
            f32x4 a0 = *(const f32x4*)ar;
            f32x4 a1 = *(const f32x4*)(ar + 4);
            #pragma unroll
            for (int j = 0; j < 4; ++j) { af[j] = (_Float16)a0[j]; af[4 + j] = (_Float16)a1[j]; }
        } else {
            af = *(const half8*)(Ah + arow + koff);
        }
        #pragma unroll
        for (int j = 0; j < 4; ++j) {
            int n = nb + j * 16 + lo;
            half8 bf = *(const half8*)(BT + (size_t)n * SS + koff);
            acc[j] = __builtin_amdgcn_mfma_f32_16x16x32_f16(af, bf, acc[j], 0, 0, 0);
        }
    }

    #pragma unroll
    for (int j = 0; j < 4; ++j) {
        #pragma unroll
        for (int i = 0; i < 4; ++i) {
            int m = mbase + q * 4 + i;
            int n = nb + j * 16 + lo;
            if (MODE == 0) {
                ((_Float16*)Outp)[(size_t)m * SS + n] = (_Float16)acc[j][i];
            } else if (MODE == 1) {
                ((float*)Outp)[(size_t)m * SS + n] = acc[j][i];
            } else {
                int t2 = m & (TT - 1);
                int b2 = m >> 11;                 // T = 2048 = 2^11
                ((_Float16*)Outp)[((size_t)t2 * NB + b2) * SS + n] = (_Float16)acc[j][i];
            }
        }
    }
}

// -------------------- cooperative liquid scan: 8 WGs, weights in registers --------------------
// Same proven protocol as round 3 (fp32 z transport, agent-scope atomics, per-wave vmcnt drain
// before barrier before flag), with three latency fixes:
//  (a) PARALLEL flag poll: lanes 1..7 of wave 0 each poll one peer (1 RT/iteration, not 7).
//  (b) per-thread stats gather (issued with z gather, same RT window; fixed order -> identical
//      mu/rs bits in all WGs) -- removes serialized wave0 stats pass + one barrier.
//  (c) U[t+1] prefetch during the publish drain.
__global__ __launch_bounds__(512) void scan5_kernel(
        const _Float16* __restrict__ U,     // [T][NB][SS]
        const float* __restrict__ Amat,     // [SS][SS] fp32 (k-major rows)
        const float* __restrict__ Kmat,     // [SS][SS]
        const float* __restrict__ ab,
        const float* __restrict__ gn,
        const float* __restrict__ bt,
        _Float16* __restrict__ hs,          // [NB][T][SS] history out
        u64*      __restrict__ zmail,       // [2][NWG][512] u64  == [2][NWG][16][64] f32
        u64*      __restrict__ smail,       // [2][NWG][16] u64   == packed (S1,S2) f32 pairs
        unsigned* __restrict__ flags)       // [NWG][32] monotone step counters (128B stride)
{
    const int wg   = blockIdx.x;
    const int tid  = threadIdx.x;
    const int wv   = tid >> 6;
    const int lane = tid & 63;
    const int q    = lane >> 4;
    const int r    = lane & 15;

    __shared__ _Float16 H16[16][520];           // f16 H for MFMA A-frags
    __shared__ float    HF[16][516];            // fp32 master accumulator of H
    alignas(16) __shared__ float ZW32[16][64];  // own z slice staging (FP32)
    __shared__ float    STAT[4][16][2];         // per-MFMA-wave partial (S1,S2) per batch
    __shared__ float    GG[512];
    __shared__ float    BB[512];

    const int ub = tid & 15;            // h-update batch
    const int ug = tid >> 4;            // 0..31
    const int uc = ug * 16;             // h-update col start (slice index uc>>6 == wv)

    for (int e = tid; e < 16 * 520; e += 512) (&H16[0][0])[e] = (_Float16)0.f;
    for (int e = tid; e < 16 * 516; e += 512) (&HF[0][0])[e] = 0.f;
    GG[tid] = gn[tid];
    BB[tid] = bt[tid];

    const bool mf = (wv < 4);
    const int ccol = wg * 64 + (wv & 3) * 16 + r;

    // one-time weight preload into registers (f16)
    half8 wA[16], wK[16];
    if (mf) {
        for (int ks = 0; ks < 16; ++ks) {
            half8 a, k;
            #pragma unroll
            for (int jj = 0; jj < 8; ++jj) {
                int kk = ks * 32 + q * 8 + jj;
                a[jj] = (_Float16)Amat[(size_t)kk * SS + ccol];
                k[jj] = (_Float16)Kmat[(size_t)kk * SS + ccol];
            }
            wA[ks] = a; wK[ks] = k;
        }
    }
    const float abreg = ab[ccol];
    float uprev[4] = {0.f, 0.f, 0.f, 0.f};
    float ucur[4]  = {0.f, 0.f, 0.f, 0.f};
    if (mf) {
        #pragma unroll
        for (int i = 0; i < 4; ++i)
            ucur[i] = (float)U[(size_t)(q * 4 + i) * SS + ccol];   // t = 0
    }
    __syncthreads();

    for (int t = 0; t < TT; ++t) {
        const int par = t & 1;

        if (mf) {
            f32x4 zA = {0.f, 0.f, 0.f, 0.f}, zK = {0.f, 0.f, 0.f, 0.f};
            #pragma unroll
            for (int ks = 0; ks < 16; ++ks) {
                half8 hf = *(const half8*)(&H16[r][ks * 32 + q * 8]);
                zA = __builtin_amdgcn_mfma_f32_16x16x32_f16(hf, wA[ks], zA, 0, 0, 0);
                zK = __builtin_amdgcn_mfma_f32_16x16x32_f16(hf, wK[ks], zK, 0, 0, 0);
            }

            float z[4];
            #pragma unroll
            for (int i = 0; i < 4; ++i) {
                z[i] = zA[i] + ucur[i] + abreg + zK[i] * uprev[i];
                uprev[i] = ucur[i];
                ZW32[q * 4 + i][(wv & 3) * 16 + r] = z[i];   // fp32 LDS transpose stage
            }

            // per-tile LN moments (fp32): reduce over 16 cols (r bits)
            float s1[4], s2[4];
            #pragma unroll
            for (int i = 0; i < 4; ++i) { s1[i] = z[i]; s2[i] = z[i] * z[i]; }
            #pragma unroll
            for (int off = 1; off < 16; off <<= 1) {
                #pragma unroll
                for (int i = 0; i < 4; ++i) {
                    s1[i] += __shfl_xor(s1[i], off, 64);
                    s2[i] += __shfl_xor(s2[i], off, 64);
                }
            }
            if (r == 0) {
                #pragma unroll
                for (int i = 0; i < 4; ++i) {
                    STAT[wv][q * 4 + i][0] = s1[i];
                    STAT[wv][q * 4 + i][1] = s2[i];
                }
            }
        }
        __syncthreads();                                   // B1: ZW32/STAT ready

        // publish z slice: 512 threads x one contiguous 8B agent-scope atomic store (fp32 pairs)
        {
            u64 v = ((const u64*)ZW32)[tid];
            __hip_atomic_store(&zmail[((size_t)par * NWG + wg) * 512 + tid], v,
                               __ATOMIC_RELAXED, __HIP_MEMORY_SCOPE_AGENT);
        }
        // publish WG-partial LN moments: packed (S1,S2) u64 per batch
        if (wv == 0 && lane < 16) {
            float S1 = STAT[0][lane][0] + STAT[1][lane][0] + STAT[2][lane][0] + STAT[3][lane][0];
            float S2 = STAT[0][lane][1] + STAT[1][lane][1] + STAT[2][lane][1] + STAT[3][lane][1];
            union { float f[2]; u64 u; } pk;
            pk.f[0] = S1; pk.f[1] = S2;
            __hip_atomic_store(&smail[((size_t)par * NWG + wg) * 16 + lane], pk.u,
                               __ATOMIC_RELAXED, __HIP_MEMORY_SCOPE_AGENT);
        }
        // prefetch next-step U while the publish stores drain (consumed already this step)
        if (mf) {
            const int tn = (t + 1 < TT) ? (t + 1) : t;
            #pragma unroll
            for (int i = 0; i < 4; ++i)
                ucur[i] = (float)U[((size_t)tn * NB + (q * 4 + i)) * SS + ccol];
        }
        __builtin_amdgcn_s_waitcnt(0);
        __syncthreads();                                   // B2: all publishes at coherence point

        // flag publish + PARALLEL poll (lanes 1..7 each watch one peer)
        if (tid == 0) {
            __builtin_amdgcn_fence(__ATOMIC_RELEASE, "agent");
            __hip_atomic_store(&flags[wg * 32], (unsigned)(t + 1),
                               __ATOMIC_RELAXED, __HIP_MEMORY_SCOPE_AGENT);
        }
        if (wv == 0 && lane >= 1 && lane < NWG) {
            unsigned* fp = &flags[((wg + lane) & (NWG - 1)) * 32];
            while (__hip_atomic_load(fp, __ATOMIC_RELAXED, __HIP_MEMORY_SCOPE_AGENT)
                   < (unsigned)(t + 1)) {}
        }
        if (tid == 0) __builtin_amdgcn_fence(__ATOMIC_ACQUIRE, "agent");
        __syncthreads();                                   // B3: all WGs published step t

        // gather this thread's 16 z values (batch ub, cols uc..uc+15), fp32
        float zz[16];
        if (wv == wg) {                                    // own slice: read LDS copy
            #pragma unroll
            for (int i = 0; i < 16; ++i) zz[i] = ZW32[ub][(uc & 63) + i];
        } else {
            union { u64 u[8]; float f[16]; } zu;
            const u64* src = &zmail[(((size_t)par * NWG + wv) * 16 + ub) * 32 + ((uc & 63) >> 1)];
            #pragma unroll
            for (int i = 0; i < 8; ++i)
                zu.u[i] = __hip_atomic_load(src + i, __ATOMIC_RELAXED, __HIP_MEMORY_SCOPE_AGENT);
            #pragma unroll
            for (int i = 0; i < 16; ++i) zz[i] = zu.f[i];
        }

        // per-thread global LN stats (fixed ascending order -> identical bits in every WG)
        float S1 = 0.f, S2 = 0.f;
        #pragma unroll
        for (int i = 0; i < NWG; ++i) {
            union { u64 u; float f[2]; } pk;
            pk.u = __hip_atomic_load(&smail[((size_t)par * NWG + i) * 16 + ub],
                                     __ATOMIC_RELAXED, __HIP_MEMORY_SCOPE_AGENT);
            S1 += pk.f[0]; S2 += pk.f[1];
        }
        const float mu  = S1 * (1.0f / SS);
        const float var = S2 * (1.0f / SS) - mu * mu;
        const float rs  = rsqrtf(var + 1e-5f);

        // replicated LN + exact GELU + h update (16 elems/thread), identical in all WGs
        half8 hh0, hh1;
        #pragma unroll
        for (int i4 = 0; i4 < 4; ++i4) {
            f32x4 gq = *(const f32x4*)&GG[uc + i4 * 4];
            f32x4 bq = *(const f32x4*)&BB[uc + i4 * 4];
            f32x4 hq = *(const f32x4*)&HF[ub][uc + i4 * 4];
            #pragma unroll
            for (int jj = 0; jj < 4; ++jj) {
                const int e = i4 * 4 + jj;
                float zn = (zz[e] - mu) * rs * gq[jj] + bq[jj];
                float ge = 0.5f * zn * (1.0f + erff(zn * 0.70710678118654752f));
                float hv = hq[jj] + ge;
                hq[jj] = hv;
                if (e < 8) hh0[e] = (_Float16)hv; else hh1[e - 8] = (_Float16)hv;
            }
            *(f32x4*)&HF[ub][uc + i4 * 4] = hq;
        }
        *(half8*)(&H16[ub][uc])     = hh0;
        *(half8*)(&H16[ub][uc + 8]) = hh1;
        if (wv == wg) {   // slice owner writes history
            _Float16* hd = hs + ((size_t)ub * TT + t) * SS + uc;
            *(half8*)(hd)     = hh0;
            *(half8*)(hd + 8) = hh1;
        }
        __syncthreads();                                   // B5: H16/ZW32/STAT free for next step
    }
}

// -------------------- host launch --------------------
extern "C" void kernel_launch(void* const* d_in, const int* in_sizes, int n_in,
                              void* d_out, int out_size, void* d_ws, size_t ws_size,
                              hipStream_t stream) {
    const float* x   = (const float*)d_in[0];
    const float* A0  = (const float*)d_in[1];
    const float* B0  = (const float*)d_in[2];
    const float* C0  = (const float*)d_in[3];
    const float* K0  = (const float*)d_in[4];
    const float* ab0 = (const float*)d_in[5];
    const float* g0  = (const float*)d_in[6];
    const float* bt0 = (const float*)d_in[7];
    const float* A1  = (const float*)d_in[8];
    const float* B1  = (const float*)d_in[9];
    const float* C1  = (const float*)d_in[10];
    const float* K1  = (const float*)d_in[11];
    const float* ab1 = (const float*)d_in[12];
    const float* g1  = (const float*)d_in[13];
    const float* bt1 = (const float*)d_in[14];

    char* ws = (char*)d_ws;
    size_t off = 0;
    auto alloc = [&](size_t bytes) { size_t o = off; off = (off + bytes + 255) & ~(size_t)255; return o; };

    const size_t BUF_BYTES = (size_t)NB * TT * SS * 2;   // 33.5 MB f16
    const size_t WP_BYTES  = (size_t)SS * SS * 2;        // 512 KB f16

    _Float16* U0  = (_Float16*)(ws + alloc(BUF_BYTES));  // [t][b][c]
    _Float16* U1  = (_Float16*)(ws + alloc(BUF_BYTES));  // [t][b][c]
    _Float16* hs0 = (_Float16*)(ws + alloc(BUF_BYTES));  // [b][t][c]
    _Float16* hs1 = (_Float16*)(ws + alloc(BUF_BYTES));  // [b][t][c]
    _Float16* B0T = (_Float16*)(ws + alloc(WP_BYTES));
    _Float16* WT  = (_Float16*)(ws + alloc(WP_BYTES));
    _Float16* C1T = (_Float16*)(ws + alloc(WP_BYTES));
    float*    Wf  = (float*)(ws + alloc((size_t)SS * SS * 4));
    u64*      zmail  = (u64*)(ws + alloc((size_t)2 * NWG * 512 * 8));   // 64 KB
    u64*      smail  = (u64*)(ws + alloc((size_t)2 * NWG * 16 * 8));
    unsigned* flags0 = (unsigned*)(ws + alloc((size_t)NWG * 32 * 4));   // contiguous with flags1
    unsigned* flags1 = (unsigned*)(ws + alloc((size_t)NWG * 32 * 4));

    // zero both scans' flags first (stream-ordered; safe under graph replay)
    zinit_kernel<<<1, 512, 0, stream>>>(flags0, 2 * NWG * 32);
    (void)flags1;

    // weight preps
    tcvt_kernel<<<256, 256, 0, stream>>>(B0, B0T);
    tcvt_kernel<<<256, 256, 0, stream>>>(C1, C1T);
    wmm_kernel<<<512, 256, 0, stream>>>(C0, B1, Wf);     // W = C0 @ B1 (layer-fold)
    tcvt_kernel<<<256, 256, 0, stream>>>(Wf, WT);

    // U0 = x @ B0, scan layout [t][b][c]
    gemm_kernel<0, 2><<<4096, 256, 0, stream>>>((const void*)x, B0T, (void*)U0);

    // layer-0 cooperative scan
    scan5_kernel<<<NWG, 512, 0, stream>>>(U0, A0, K0, ab0, g0, bt0, hs0, zmail, smail, flags0);

    // U1 = hs0 @ (C0@B1), scan layout
    gemm_kernel<1, 2><<<4096, 256, 0, stream>>>((const void*)hs0, WT, (void*)U1);

    // layer-1 cooperative scan
    scan5_kernel<<<NWG, 512, 0, stream>>>(U1, A1, K1, ab1, g1, bt1, hs1, zmail, smail, flags1);

    // out = hs1 @ C1 (fp32 [b][t][c])
    gemm_kernel<1, 1><<<4096, 256, 0, stream>>>((const void*)hs1, C1T, d_out);
}